// Round 6
// baseline (115.490 us; speedup 1.0000x reference)
//
#include <hip/hip_runtime.h>
#include <math.h>

#define BB 8
#define HH 256
#define KK 256
#define EE 128
#define HJ 4                  // h rows per block in K1
#define NBLK (BB * HH / HJ)   // 512 blocks
#define NBIN 1024             // histogram bins, padded 1000 -> 1024

// DPP-based add: x + dpp_mov(x). Template args keep ctrl a compile-time const.
template <int CTRL, int RM>
__device__ __forceinline__ float dpp_add(float x) {
    int d = __builtin_amdgcn_update_dpp(0, __float_as_int(x), CTRL, RM, 0xf, true);
    return x + __int_as_float(d);
}
// Sum over each 32-lane half; valid in lanes 31 and 63.
__device__ __forceinline__ float dpp_reduce_half(float x) {
    x = dpp_add<0x111, 0xf>(x);  // row_shr:1
    x = dpp_add<0x112, 0xf>(x);  // row_shr:2
    x = dpp_add<0x114, 0xf>(x);  // row_shr:4
    x = dpp_add<0x118, 0xf>(x);  // row_shr:8
    x = dpp_add<0x142, 0xa>(x);  // row_bcast:15 -> lanes 31,63 hold 32-lane sums
    return x;
}
// Sum over all 64 lanes; valid in lane 63.
__device__ __forceinline__ float dpp_reduce_wave(float x) {
    x = dpp_reduce_half(x);
    x = dpp_add<0x143, 0xc>(x);  // row_bcast:31 -> lane 63 holds 64-lane sum
    return x;
}

// ---------------- K1: per (b, 4-h): p -> LDS histogram over value-vocab bins.
// Key insight: o[b,h,:] = sum_bins hist[bin]*V[bin,:], and sum over h commutes
// into the histogram, so we never gather value rows per (b,h).
__global__ __launch_bounds__(256) void kvmn_attn_hist(
    const float* __restrict__ hidden,     // [B,H,E]
    const float* __restrict__ key_emb,    // [VOCAB,E]
    const int*   __restrict__ key_seq,    // [B,K]
    const int*   __restrict__ value_seq,  // [B,H,K]
    const int*   __restrict__ mask,       // [B,H,K]
    float* __restrict__ part_hist,        // [NBLK, NBIN]
    int*   __restrict__ c_part)           // [NBLK] count of valid h in block
{
    __shared__ float sh_u[HJ][KK];
    __shared__ float hist[NBIN];
    __shared__ float fslot[HJ][4];
    __shared__ int   islot[HJ][4];

    const int bid  = blockIdx.x;
    const int b    = bid >> 6;            // / 64
    const int h0   = (bid & 63) * HJ;
    const int tid  = threadIdx.x;
    const int w    = tid >> 6;
    const int lane = tid & 63;
    const int half = lane >> 5;
    const int sub  = lane & 31;

    // k == tid: this thread's key index (broadcast to the wave via shfl later)
    const int ksreg = key_seq[b * KK + tid];

    // hidden fragments for the 4 h rows (e = sub*4 .. sub*4+3)
    float4 h4[HJ];
    #pragma unroll
    for (int j = 0; j < HJ; ++j)
        h4[j] = *(const float4*)&hidden[(size_t)(b * HH + h0 + j) * EE + sub * 4];

    // zero histogram (1 float4 per thread)
    *(float4*)&hist[tid * 4] = make_float4(0.f, 0.f, 0.f, 0.f);

    const float inv_scale = 0.08838834764831845f; // 1/sqrt(128)

    // ---- phase 1: each key row read ONCE, dotted against all 4 h rows.
    // (w, half) handles k in [w*64 + half*32, +32).
    #pragma unroll 8
    for (int i = 0; i < 32; ++i) {
        const int    row = __shfl(ksreg, half * 32 + i, 64);
        const float4 kv  = *(const float4*)&key_emb[(size_t)row * EE + sub * 4];
        const int    k2  = w * 64 + half * 32 + i;
        #pragma unroll
        for (int j = 0; j < HJ; ++j) {
            float part = kv.x * h4[j].x + kv.y * h4[j].y + kv.z * h4[j].z + kv.w * h4[j].w;
            part = dpp_reduce_half(part);
            if (sub == 31) sh_u[j][k2] = part * inv_scale;
        }
    }
    __syncthreads();

    // ---- phase 2: per h row: d = exp(u)*mask, block denom, validity flag
    float d[HJ];
    int   vs[HJ];
    #pragma unroll
    for (int j = 0; j < HJ; ++j) {
        const size_t idx = (size_t)(b * HH + h0 + j) * KK + tid;
        const int m = mask[idx];
        vs[j] = value_seq[idx];
        d[j]  = expf(sh_u[j][tid]) * (float)m;
        const float s = dpp_reduce_wave(d[j]);
        if (lane == 63) fslot[j][w] = s;
        const int any = __any(m != 0 && vs[j] != 0);   // o-row nonzero iff any
        if (lane == 0) islot[j][w] = any ? 1 : 0;
    }
    __syncthreads();

    // ---- p = d/(denom+1e-10); scatter into LDS histogram (p==0 adds nothing)
    #pragma unroll
    for (int j = 0; j < HJ; ++j) {
        const float denom = fslot[j][0] + fslot[j][1] + fslot[j][2] + fslot[j][3];
        const float p = d[j] * (1.0f / (denom + 1e-10f));
        atomicAdd(&hist[vs[j]], p);
    }
    if (tid == 0) {
        int c = 0;
        #pragma unroll
        for (int j = 0; j < HJ; ++j)
            c += (islot[j][0] | islot[j][1] | islot[j][2] | islot[j][3]);
        c_part[bid] = c;
    }
    __syncthreads();

    // ---- write this block's partial histogram (coalesced b128)
    *(float4*)&part_hist[(size_t)bid * NBIN + tid * 4] = *(float4*)&hist[tid * 4];
}

// ---------------- K2: per b: AggHist = sum of 64 partials; out = (AggHist x V)/c.
__global__ __launch_bounds__(512) void kvmn_finalize(
    const float* __restrict__ part_hist,  // [NBLK, NBIN]
    const int*   __restrict__ c_part,     // [NBLK]
    const float* __restrict__ value_emb,  // [FVOCAB, E]
    float* __restrict__ out)              // [B, E]
{
    __shared__ float H[NBIN];
    __shared__ float gs[4][EE];
    __shared__ int   csh[64];
    __shared__ float cval;

    const int b   = blockIdx.x;
    const int tid = threadIdx.x;          // 0..511

    // reduce 64 partial hists (float2 per thread covers 1024 bins)
    float2 acc2 = make_float2(0.f, 0.f);
    #pragma unroll 8
    for (int i = 0; i < 64; ++i) {
        const float2 v = *(const float2*)&part_hist[(size_t)(b * 64 + i) * NBIN + tid * 2];
        acc2.x += v.x;
        acc2.y += v.y;
    }
    *(float2*)&H[tid * 2] = acc2;
    if (tid < 64) csh[tid] = c_part[b * 64 + tid];
    __syncthreads();
    if (tid == 0) {
        int c = 0;
        #pragma unroll
        for (int i = 0; i < 64; ++i) c += csh[i];
        cval = (float)c;
    }

    // dense GEMM: out[b,e] = sum_bins H[bin] * V[bin,e]; 4-way k-split
    const int e  = tid & 127;
    const int qt = tid >> 7;              // 0..3, 250 bins each (1000 total)
    float acc = 0.f;
    const int bin0 = qt * 250;
    #pragma unroll 5
    for (int bin = bin0; bin < bin0 + 250; ++bin)
        acc += H[bin] * value_emb[(size_t)bin * EE + e];  // H: LDS broadcast
    gs[qt][e] = acc;
    __syncthreads();
    if (tid < 128)
        out[b * EE + tid] = (gs[0][tid] + gs[1][tid] + gs[2][tid] + gs[3][tid]) / cval;
}

extern "C" void kernel_launch(void* const* d_in, const int* in_sizes, int n_in,
                              void* d_out, int out_size, void* d_ws, size_t ws_size,
                              hipStream_t stream) {
    const float* hidden    = (const float*)d_in[0];
    const float* key_emb   = (const float*)d_in[1];
    const float* value_emb = (const float*)d_in[2];
    const int*   key_seq   = (const int*)d_in[3];
    const int*   value_seq = (const int*)d_in[4];
    const int*   mask      = (const int*)d_in[5];

    float* part_hist = (float*)d_ws;                                  // 2 MB
    int*   c_part    = (int*)((char*)d_ws + (size_t)NBLK * NBIN * 4); // 2 KB

    kvmn_attn_hist<<<NBLK, 256, 0, stream>>>(hidden, key_emb, key_seq,
                                             value_seq, mask, part_hist, c_part);
    kvmn_finalize<<<BB, 512, 0, stream>>>(part_hist, c_part, value_emb, (float*)d_out);
    (void)in_sizes; (void)n_in; (void)out_size; (void)ws_size;
}